// Round 11
// baseline (2469.267 us; speedup 1.0000x reference)
//
#include <hip/hip_runtime.h>
#include <hip/hip_bf16.h>

// BeamDecoder: greedy CVRP-style decode.
// s_i(step) = c*( G[last,i] + (load/cap)*u_i )   (v==0 since bq==0; folded)
// R11: R10 failed structurally — the tier-2 prefetch committed to VGPRs forced
// s_waitcnt vmcnt(0) every step. Fix: prefetch the K=128 candidate list with
// __builtin_amdgcn_global_load_lds into parity LDS buffers (no register
// writeback); the only vmcnt wait sits right before the LDS read, one full
// step after issue -> latency hidden. Entries baked as (g, idx, u[idx],
// dem[idx]) so no dependent gathers; visited = 256 B LDS bitmask.
// Selection/certification verbatim R9: exact in-list argmax w/ min-index
// ties; certified global iff rbv > thr + lr*umax + 0.5; else full-row scan.
// Scores exact via deferred pass (same fmaf(u,lr,g)*C0 as R3-R10).

#define NN 2048
#define HH 1024
#define TSTEPS (NN + NN / 8)   // 2304
#define TILE 64
#define KT 16
#define KMID 128

// ---------------- pack Wq[:, :H] into ld=1024 buffer ----------------
__global__ __launch_bounds__(256) void prep_wqh(const float* __restrict__ Wq,
                                                float* __restrict__ Wqh) {
  int id = blockIdx.x * 256 + threadIdx.x;
  int r = id >> 10, c = id & 1023;
  Wqh[id] = Wq[r * (HH + 2) + c];
}

// ---------------- NT GEMM: C[M,N] = A[M,K] @ B[N,K]^T (+ bias[n]) ----------------
__global__ __launch_bounds__(256) void gemm_nt(const float* __restrict__ A, int lda,
                                               const float* __restrict__ B, int ldb,
                                               float* __restrict__ C, int ldc,
                                               int K, const float* __restrict__ bias) {
  __shared__ float As[KT][TILE + 4];
  __shared__ float Bs[KT][TILE + 4];
  const int i0 = blockIdx.y * TILE;
  const int j0 = blockIdx.x * TILE;
  const int t = threadIdx.x;
  const int srow = t >> 2, sq = t & 3;
  const int tx = t & 15, ty = t >> 4;
  float acc[4][4] = {};
  for (int k0 = 0; k0 < K; k0 += KT) {
    float4 av = *(const float4*)&A[(size_t)(i0 + srow) * lda + k0 + sq * 4];
    float4 bv = *(const float4*)&B[(size_t)(j0 + srow) * ldb + k0 + sq * 4];
    __syncthreads();
    As[sq * 4 + 0][srow] = av.x; As[sq * 4 + 1][srow] = av.y;
    As[sq * 4 + 2][srow] = av.z; As[sq * 4 + 3][srow] = av.w;
    Bs[sq * 4 + 0][srow] = bv.x; Bs[sq * 4 + 1][srow] = bv.y;
    Bs[sq * 4 + 2][srow] = bv.z; Bs[sq * 4 + 3][srow] = bv.w;
    __syncthreads();
#pragma unroll
    for (int k = 0; k < KT; ++k) {
      float4 a4 = *(const float4*)&As[k][ty * 4];
      float4 b4 = *(const float4*)&Bs[k][tx * 4];
      float a[4] = {a4.x, a4.y, a4.z, a4.w};
      float b[4] = {b4.x, b4.y, b4.z, b4.w};
#pragma unroll
      for (int m = 0; m < 4; ++m)
#pragma unroll
        for (int n = 0; n < 4; ++n) acc[m][n] = fmaf(a[m], b[n], acc[m][n]);
    }
  }
  float bb[4] = {0.f, 0.f, 0.f, 0.f};
  if (bias) {
#pragma unroll
    for (int n = 0; n < 4; ++n) bb[n] = bias[j0 + tx * 4 + n];
  }
#pragma unroll
  for (int m = 0; m < 4; ++m) {
    float4 st = {acc[m][0] + bb[0], acc[m][1] + bb[1], acc[m][2] + bb[2], acc[m][3] + bb[3]};
    *(float4*)&C[(size_t)(i0 + ty * 4 + m) * ldc + j0 + tx * 4] = st;
  }
}

// ---------------- u_i = K_i . Wq[:,H], v_i = K_i . bq  (one wave per row) ---------
__global__ __launch_bounds__(64) void uv_k(const float* __restrict__ Kmat,
                                           const float* __restrict__ Wq,
                                           const float* __restrict__ bq,
                                           float* __restrict__ u, float* __restrict__ v) {
  int i = blockIdx.x;
  int lane = threadIdx.x;
  float su = 0.f, sv = 0.f;
#pragma unroll
  for (int m = 0; m < HH / 64; ++m) {
    int j = lane + 64 * m;
    float kv = Kmat[(size_t)i * HH + j];
    su = fmaf(kv, Wq[(size_t)j * (HH + 2) + HH], su);
    sv = fmaf(kv, bq[j], sv);
  }
#pragma unroll
  for (int off = 32; off; off >>= 1) {
    su += __shfl_down(su, off, 64);
    sv += __shfl_down(sv, off, 64);
  }
  if (lane == 0) { u[i] = su; v[i] = sv; }
}

// ---------------- umax = max |u| ----------------
__global__ __launch_bounds__(256) void umax_k(const float* __restrict__ u,
                                              float* __restrict__ umaxp) {
  __shared__ float sm[256];
  int t = threadIdx.x;
  float m = 0.f;
  for (int i = t; i < NN; i += 256) m = fmaxf(m, fabsf(u[i]));
  sm[t] = m;
  __syncthreads();
  for (int s = 128; s; s >>= 1) {
    if (t < s) sm[t] = fmaxf(sm[t], sm[t + s]);
    __syncthreads();
  }
  if (t == 0) *umaxp = sm[0];
}

// ---------------- per-row exact top-KMID by g: 4-pass radix-select ----------------
// Entries baked as (g, idx, u[idx], dem[idx]) — 16 B, one ds_read_b128 in decode.
__device__ __forceinline__ unsigned f2key(float f) {
  unsigned x = __float_as_uint(f);
  return x ^ ((x >> 31) ? 0xFFFFFFFFu : 0x80000000u);
}
__device__ __forceinline__ float key2f(unsigned k) {
  unsigned x = (k & 0x80000000u) ? (k ^ 0x80000000u) : ~k;
  return __uint_as_float(x);
}
__global__ __launch_bounds__(256) void prep_cand(const float* __restrict__ GT,
                                                 const float* __restrict__ u,
                                                 const float* __restrict__ dem,
                                                 uint4* __restrict__ cand,
                                                 float* __restrict__ thr) {
  __shared__ float rowv[NN];
  __shared__ int hist[256];
  __shared__ int s_d, s_need, s_gt, s_eq;
  const int row = blockIdx.x, t = threadIdx.x;
  for (int i = t; i < NN; i += 256) rowv[i] = GT[(size_t)row * NN + i];
  __syncthreads();
  unsigned prefix = 0;
  int need = KMID;
  for (int pass = 0; pass < 4; ++pass) {
    hist[t] = 0;
    __syncthreads();
    const int shift = 24 - 8 * pass;
    for (int i = t; i < NN; i += 256) {
      unsigned k = f2key(rowv[i]);
      if (pass == 0 || (k >> (shift + 8)) == (prefix >> (shift + 8)))
        atomicAdd(&hist[(k >> shift) & 0xFF], 1);
    }
    __syncthreads();
    if (t == 0) {
      int cum = 0, d = 255;
      for (; d > 0; --d) {
        if (cum + hist[d] >= need) break;
        cum += hist[d];
      }
      s_d = d;
      s_need = need - cum;
    }
    __syncthreads();
    prefix |= ((unsigned)s_d) << shift;
    need = s_need;
    __syncthreads();
  }
  const unsigned thrk = prefix;
  if (t == 0) { s_gt = 0; s_eq = 0; thr[row] = key2f(thrk); }
  __syncthreads();
  for (int i = t; i < NN; i += 256) {
    if (f2key(rowv[i]) > thrk) {
      int p = atomicAdd(&s_gt, 1);
      cand[(size_t)row * KMID + p] =
          make_uint4(__float_as_uint(rowv[i]), (unsigned)i,
                     __float_as_uint(u[i]), __float_as_uint(dem[i]));
    }
  }
  __syncthreads();
  const int cgt = s_gt;
  for (int i = t; i < NN; i += 256) {
    if (f2key(rowv[i]) == thrk) {
      int p = atomicAdd(&s_eq, 1);
      if (p < KMID - cgt)
        cand[(size_t)row * KMID + cgt + p] =
            make_uint4(__float_as_uint(rowv[i]), (unsigned)i,
                       __float_as_uint(u[i]), __float_as_uint(dem[i]));
    }
  }
}

// ---------------- L2 pre-warm ----------------
__global__ __launch_bounds__(256) void warm_k(const float* __restrict__ a, int n,
                                              const float* __restrict__ b, int m,
                                              float* __restrict__ sink) {
  float s = 0.f;
  const float4* a4 = (const float4*)a;
  for (int i = threadIdx.x; i < n / 4; i += 256) {
    float4 x = a4[i];
    s += x.x + x.y + x.z + x.w;
  }
  for (int i = threadIdx.x; i < m; i += 256) s += b[i];
  if (s == 1.2345e-30f) sink[blockIdx.x] = s;
}

// DPP merge of (bv,bi): max value, smallest index on ties.
#define DPP_MERGE2(CTRL)                                                      \
  {                                                                           \
    int ovb = __builtin_amdgcn_update_dpp(                                    \
        (int)0xFF800000, __float_as_int(bv), (CTRL), 0xf, 0xf, false);        \
    int oib = __builtin_amdgcn_update_dpp(                                    \
        0x7fffffff, bi, (CTRL), 0xf, 0xf, false);                             \
    float ov = __int_as_float(ovb);                                           \
    if (ov > bv || (ov == bv && oib < bi)) { bv = ov; bi = oib; }             \
  }

// async 16B/lane global->LDS copy: lane i writes lds_base + i*16
__device__ __forceinline__ void gload_lds16(const uint4* g, uint4* l) {
  __builtin_amdgcn_global_load_lds(
      (const __attribute__((address_space(1))) void*)g,
      (__attribute__((address_space(3))) void*)l, 16, 0, 0);
}

// ---------------- sequential decode: ONE wave ------------------------------------
__global__ __launch_bounds__(64, 1) void decode(const float* __restrict__ GT,
                                                const uint4* __restrict__ cand,
                                                const float* __restrict__ thrp,
                                                const float* __restrict__ umaxp,
                                                const float* __restrict__ u,
                                                const float* __restrict__ demands,
                                                const int* __restrict__ capp,
                                                const int* __restrict__ depotp,
                                                int* __restrict__ tourW,
                                                float* __restrict__ lrW,
                                                float* __restrict__ out) {
  __shared__ __align__(16) float s_dd[NN];        // demands, +inf = visited (tier-3)
  __shared__ __align__(16) float s_thr[NN];       // K=128 thresholds
  __shared__ __align__(16) unsigned s_vis[NN / 32];  // bit 1 = unvisited
  __shared__ __align__(16) uint4 s_pf[2][KMID];   // parity prefetch buffers

  const int lane = threadIdx.x;
  const int depot = *depotp;
  const float capf = (float)(*capp);
  const float umaxv = *umaxp;
  const float INF = __builtin_inff();
  const float NEGINF = -INF;
  const float C0 = 0.015625f;   // ALPHA / sqrt(HID), exact power of two

  for (int i = lane; i < NN; i += 64) {
    s_dd[i] = demands[i];
    s_thr[i] = thrp[i];
  }
  if (lane == 0) {
    for (int i = 0; i < NN / 32; ++i) s_vis[i] = 0xFFFFFFFFu;
  }
  __syncthreads();
  if (lane == 0) {
    s_dd[depot] = INF;
    s_vis[depot >> 5] &= ~(1u << (depot & 31));
  }

  float uu[32];  // R9 layout for tier-3: uu[r*4+j] = u[4*(r*64+lane)+j]
#pragma unroll
  for (int r = 0; r < 8; ++r) {
    float4 u4 = ((const float4*)u)[r * 64 + lane];
    uu[r * 4 + 0] = u4.x; uu[r * 4 + 1] = u4.y;
    uu[r * 4 + 2] = u4.z; uu[r * 4 + 3] = u4.w;
  }
  const float4* dd4 = (const float4*)s_dd;

  int done = 0, ntaken = 0, lasts = depot;
  float load = capf;
  float lr = load / capf;  // same fp32 division as reference

  // issue step-0 prefetch (depot row) into buffer 0 — no register writeback
  gload_lds16(cand + (size_t)depot * KMID + lane, &s_pf[0][0]);
  gload_lds16(cand + (size_t)depot * KMID + 64 + lane, &s_pf[0][64]);

  for (int step = 0; step < TSTEPS; ++step) {
    if (done) {  // ref emits (depot, 0) forever once done
      for (int q = step + lane; q < TSTEPS; q += 64) {
        tourW[q] = depot;
        lrW[q] = -1.0f;
      }
      break;
    }
    const int par = step & 1;
    // ---- the only wait on the chain: drain the prefetch issued last step
    asm volatile("s_waitcnt vmcnt(0)" ::: "memory");
    uint4 e0 = s_pf[par][lane];
    uint4 e1 = s_pf[par][64 + lane];

    float bv = NEGINF;
    int bi = 0x7fffffff;
    {
      float g0 = __uint_as_float(e0.x); int j0 = (int)e0.y;
      float u0 = __uint_as_float(e0.z); float d0 = __uint_as_float(e0.w);
      float g1 = __uint_as_float(e1.x); int j1 = (int)e1.y;
      float u1 = __uint_as_float(e1.z); float d1 = __uint_as_float(e1.w);
      bool f0 = (d0 <= load) && ((s_vis[j0 >> 5] >> (j0 & 31)) & 1u);
      bool f1 = (d1 <= load) && ((s_vis[j1 >> 5] >> (j1 & 31)) & 1u);
      float t0 = fmaf(u0, lr, g0);  // identical expression to the full scan
      float t1 = fmaf(u1, lr, g1);
      if (f0 && (t0 > bv || (t0 == bv && j0 < bi))) { bv = t0; bi = j0; }
      if (f1 && (t1 > bv || (t1 == bv && j1 < bi))) { bv = t1; bi = j1; }
    }
    DPP_MERGE2(0x111); DPP_MERGE2(0x112); DPP_MERGE2(0x114);
    DPP_MERGE2(0x118); DPP_MERGE2(0x142); DPP_MERGE2(0x143);
    float rbv = __int_as_float(__builtin_amdgcn_readlane(__float_as_int(bv), 63));
    int rbi = __builtin_amdgcn_readlane(bi, 63);

    // certification: any node outside the list has g <= thr, |u| <= umax
    int take, nxt;
    if (rbv > fmaf(lr, umaxv, s_thr[lasts]) + 0.5f) {
      take = 1; nxt = rbi;  // certified global argmax (incl. tie semantics)
    } else {
      // ---- fallback: R9-verbatim exact full-row scan
      const float4* rowp = (const float4*)(GT + (size_t)lasts * NN);
      float bv = NEGINF;
      int bi = NN;
#pragma unroll
      for (int r = 0; r < 8; ++r) {
        float4 g4 = rowp[r * 64 + lane];
        float4 d4 = dd4[r * 64 + lane];
        float gl[4] = {g4.x, g4.y, g4.z, g4.w};
        float dl[4] = {d4.x, d4.y, d4.z, d4.w};
        float cv = NEGINF;
        int cj = 0;
#pragma unroll
        for (int j = 0; j < 4; ++j) {
          float tt = fmaf(uu[r * 4 + j], lr, gl[j]);
          bool feas = (dl[j] <= load);
          if (feas && tt > cv) { cv = tt; cj = j; }
        }
        if (cv > bv) { bv = cv; bi = 4 * (r * 64 + lane) + cj; }  // asc r: first-max
      }
      DPP_MERGE2(0x111); DPP_MERGE2(0x112); DPP_MERGE2(0x114);
      DPP_MERGE2(0x118); DPP_MERGE2(0x142); DPP_MERGE2(0x143);
      float fbv = __int_as_float(__builtin_amdgcn_readlane(__float_as_int(bv), 63));
      int fbi = __builtin_amdgcn_readlane(bi, 63);
      take = (fbv > NEGINF);
      nxt = take ? fbi : depot;
    }

    // ---- issue next prefetch IMMEDIATELY (hides under bookkeeping + next tier-1)
    {
      const uint4* gsrc = cand + (size_t)nxt * KMID + lane;
      gload_lds16(gsrc, &s_pf[par ^ 1][0]);
      gload_lds16(gsrc + 64, &s_pf[par ^ 1][64]);
    }

    // ---- state update + off-chain output stores
    if (lane == 0) { tourW[step] = nxt; lrW[step] = take ? lr : -1.0f; }
    if (take) {
      float dsel = s_dd[nxt];   // original demand (winner is unvisited)
      load = load - dsel;       // same fp32 op sequence as reference
      ntaken++;
      if (lane == 0) {
        s_dd[nxt] = INF;
        s_vis[nxt >> 5] &= ~(1u << (nxt & 31));
      }
    } else {
      load = capf;
      if (ntaken == NN - 1) done = 1;
    }
    lasts = nxt;
    lr = load / capf;  // same fp32 division as reference
  }

  // ---- deferred exact outputs
  __threadfence();
  if (lane == 0) out[0] = (float)depot;
  for (int s = lane; s < TSTEPS; s += 64) {
    int nx = tourW[s];
    out[1 + s] = (float)nx;
    float lrs = lrW[s];
    float sc = 0.0f;
    if (lrs >= 0.0f) {
      int lastI = (s == 0) ? depot : tourW[s - 1];
      float g = GT[(size_t)lastI * NN + nx];
      sc = fmaf(u[nx], lrs, g) * C0;  // identical expression to R3-R10
    }
    out[1 + TSTEPS + s] = sc;
  }
}

extern "C" void kernel_launch(void* const* d_in, const int* in_sizes, int n_in,
                              void* d_out, int out_size, void* d_ws, size_t ws_size,
                              hipStream_t stream) {
  const float* emb     = (const float*)d_in[0];  // [N, H]
  const float* demands = (const float*)d_in[1];  // [N]
  const float* Wq      = (const float*)d_in[2];  // [H, H+2]
  const float* bq      = (const float*)d_in[3];  // [H]
  const float* Wk      = (const float*)d_in[4];  // [H, H]
  const float* bk      = (const float*)d_in[5];  // [H]
  const int* cap       = (const int*)d_in[6];
  const int* depot     = (const int*)d_in[7];
  float* out           = (float*)d_out;          // 2305 tour + 2304 scores, fp32

  char* ws = (char*)d_ws;
  float* Kmat = (float*)(ws);                         // 8 MB  [N,H]
  float* Z    = (float*)(ws + ((size_t)8 << 20));     // 8 MB  [N,H]
  float* GT   = (float*)(ws + ((size_t)16 << 20));    // 16 MB [N,N] row=last, +v
  float* Wqh  = (float*)(ws + ((size_t)32 << 20));    // 4 MB; later cand (4 MB)
  char* ex    = ws + ((size_t)36 << 20);
  float* u      = (float*)(ex);                       // 8 KB
  float* v      = (float*)(ex + 8192);                // 8 KB
  float* thr    = (float*)(ex + 16384);               // 8 KB
  float* umax   = (float*)(ex + 24576);
  float* sink   = (float*)(ex + 24832);
  int* tourW    = (int*)(ex + 40960);                 // 9.2 KB
  float* lrW    = (float*)(ex + 40960 + 9216);        // 9.2 KB
  uint4* cnd    = (uint4*)Wqh;                        // 4 MB; Wqh dead after Z

  hipLaunchKernelGGL(prep_wqh, dim3(4096), dim3(256), 0, stream, Wq, Wqh);
  hipLaunchKernelGGL(gemm_nt, dim3(HH / TILE, NN / TILE), dim3(256), 0, stream,
                     emb, HH, Wk, HH, Kmat, HH, HH, bk);
  hipLaunchKernelGGL(gemm_nt, dim3(HH / TILE, NN / TILE), dim3(256), 0, stream,
                     emb, HH, Wqh, HH, Z, HH, HH, (const float*)nullptr);
  hipLaunchKernelGGL(uv_k, dim3(NN), dim3(64), 0, stream, Kmat, Wq, bq, u, v);
  hipLaunchKernelGGL(umax_k, dim3(1), dim3(256), 0, stream, u, umax);
  hipLaunchKernelGGL(gemm_nt, dim3(NN / TILE, NN / TILE), dim3(256), 0, stream,
                     Z, HH, Kmat, HH, GT, NN, HH, v);
  hipLaunchKernelGGL(prep_cand, dim3(NN), dim3(256), 0, stream, GT, u, demands,
                     cnd, thr);
  hipLaunchKernelGGL(warm_k, dim3(128), dim3(256), 0, stream,
                     (const float*)cnd, NN * KMID * 4, thr, NN, sink);
  hipLaunchKernelGGL(decode, dim3(1), dim3(64), 0, stream, GT, cnd, thr, umax,
                     u, demands, cap, depot, tourW, lrW, out);
}

// Round 12
// 2079.708 us; speedup vs baseline: 1.1873x; 1.1873x over previous
//
#include <hip/hip_runtime.h>
#include <hip/hip_bf16.h>

// BeamDecoder: greedy CVRP-style decode.
// s_i(step) = c*( G[last,i] + (load/cap)*u_i )   (v==0 since bq==0; folded)
// R12: the dependent winner->list load (~900 cyc) is structurally exposed in
// R9-R11 (issue->consume gap is one step's ~300 cyc bookkeeping). Fix: make
// the common case load-free. Tier-1 = LDS top-5/row (bf16 g|idx) + fp32 thr5
// + bf16 u, EPS-certified top-2 (R10-verbatim math, but WITHOUT R10's
// unconditional per-step prefetch). Tier-2 = on-demand R9-verbatim exact
// K=128 uint2 list + exact certification. Tier-3 = R9-verbatim full-row
// scan. Scores exact via deferred pass (same fmaf(u,lr,g)*C0 as R3-R11).

#define NN 2048
#define HH 1024
#define TSTEPS (NN + NN / 8)   // 2304
#define TILE 64
#define KT 16
#define KMID 128
#define TSTR 6                  // LDS table row stride (5 entries + thr5)

// ---------------- pack Wq[:, :H] into ld=1024 buffer ----------------
__global__ __launch_bounds__(256) void prep_wqh(const float* __restrict__ Wq,
                                                float* __restrict__ Wqh) {
  int id = blockIdx.x * 256 + threadIdx.x;
  int r = id >> 10, c = id & 1023;
  Wqh[id] = Wq[r * (HH + 2) + c];
}

// ---------------- NT GEMM: C[M,N] = A[M,K] @ B[N,K]^T (+ bias[n]) ----------------
__global__ __launch_bounds__(256) void gemm_nt(const float* __restrict__ A, int lda,
                                               const float* __restrict__ B, int ldb,
                                               float* __restrict__ C, int ldc,
                                               int K, const float* __restrict__ bias) {
  __shared__ float As[KT][TILE + 4];
  __shared__ float Bs[KT][TILE + 4];
  const int i0 = blockIdx.y * TILE;
  const int j0 = blockIdx.x * TILE;
  const int t = threadIdx.x;
  const int srow = t >> 2, sq = t & 3;
  const int tx = t & 15, ty = t >> 4;
  float acc[4][4] = {};
  for (int k0 = 0; k0 < K; k0 += KT) {
    float4 av = *(const float4*)&A[(size_t)(i0 + srow) * lda + k0 + sq * 4];
    float4 bv = *(const float4*)&B[(size_t)(j0 + srow) * ldb + k0 + sq * 4];
    __syncthreads();
    As[sq * 4 + 0][srow] = av.x; As[sq * 4 + 1][srow] = av.y;
    As[sq * 4 + 2][srow] = av.z; As[sq * 4 + 3][srow] = av.w;
    Bs[sq * 4 + 0][srow] = bv.x; Bs[sq * 4 + 1][srow] = bv.y;
    Bs[sq * 4 + 2][srow] = bv.z; Bs[sq * 4 + 3][srow] = bv.w;
    __syncthreads();
#pragma unroll
    for (int k = 0; k < KT; ++k) {
      float4 a4 = *(const float4*)&As[k][ty * 4];
      float4 b4 = *(const float4*)&Bs[k][tx * 4];
      float a[4] = {a4.x, a4.y, a4.z, a4.w};
      float b[4] = {b4.x, b4.y, b4.z, b4.w};
#pragma unroll
      for (int m = 0; m < 4; ++m)
#pragma unroll
        for (int n = 0; n < 4; ++n) acc[m][n] = fmaf(a[m], b[n], acc[m][n]);
    }
  }
  float bb[4] = {0.f, 0.f, 0.f, 0.f};
  if (bias) {
#pragma unroll
    for (int n = 0; n < 4; ++n) bb[n] = bias[j0 + tx * 4 + n];
  }
#pragma unroll
  for (int m = 0; m < 4; ++m) {
    float4 st = {acc[m][0] + bb[0], acc[m][1] + bb[1], acc[m][2] + bb[2], acc[m][3] + bb[3]};
    *(float4*)&C[(size_t)(i0 + ty * 4 + m) * ldc + j0 + tx * 4] = st;
  }
}

// ---------------- u_i = K_i . Wq[:,H], v_i = K_i . bq  (one wave per row) ---------
__global__ __launch_bounds__(64) void uv_k(const float* __restrict__ Kmat,
                                           const float* __restrict__ Wq,
                                           const float* __restrict__ bq,
                                           float* __restrict__ u, float* __restrict__ v) {
  int i = blockIdx.x;
  int lane = threadIdx.x;
  float su = 0.f, sv = 0.f;
#pragma unroll
  for (int m = 0; m < HH / 64; ++m) {
    int j = lane + 64 * m;
    float kv = Kmat[(size_t)i * HH + j];
    su = fmaf(kv, Wq[(size_t)j * (HH + 2) + HH], su);
    sv = fmaf(kv, bq[j], sv);
  }
#pragma unroll
  for (int off = 32; off; off >>= 1) {
    su += __shfl_down(su, off, 64);
    sv += __shfl_down(sv, off, 64);
  }
  if (lane == 0) { u[i] = su; v[i] = sv; }
}

// ---------------- bf16 round-to-nearest ----------------
__device__ __forceinline__ unsigned short f2bf_rn(float f) {
  unsigned x = __float_as_uint(f);
  unsigned r = ((x >> 16) & 1u) + 0x7fffu;
  return (unsigned short)((x + r) >> 16);
}

// ---------------- umax = max |u|; zero gmaxA; pack bf16(u) ----------------
__global__ __launch_bounds__(256) void umax_k(const float* __restrict__ u,
                                              float* __restrict__ umaxp,
                                              unsigned* __restrict__ gmaxA,
                                              unsigned* __restrict__ ub16) {
  __shared__ float sm[256];
  int t = threadIdx.x;
  float m = 0.f;
  for (int i = t; i < NN; i += 256) m = fmaxf(m, fabsf(u[i]));
  sm[t] = m;
  __syncthreads();
  for (int s = 128; s; s >>= 1) {
    if (t < s) sm[t] = fmaxf(sm[t], sm[t + s]);
    __syncthreads();
  }
  if (t == 0) { *umaxp = sm[0]; *gmaxA = 0u; }
  for (int i = t; i < NN / 2; i += 256)
    ub16[i] = (unsigned)f2bf_rn(u[2 * i]) | ((unsigned)f2bf_rn(u[2 * i + 1]) << 16);
}

// ---------------- per-row exact top-KMID by g: 4-pass radix-select ----------------
__device__ __forceinline__ unsigned f2key(float f) {
  unsigned x = __float_as_uint(f);
  return x ^ ((x >> 31) ? 0xFFFFFFFFu : 0x80000000u);
}
__device__ __forceinline__ float key2f(unsigned k) {
  unsigned x = (k & 0x80000000u) ? (k ^ 0x80000000u) : ~k;
  return __uint_as_float(x);
}
__global__ __launch_bounds__(256) void prep_cand(const float* __restrict__ GT,
                                                 uint2* __restrict__ cand,
                                                 float* __restrict__ thr) {
  __shared__ float rowv[NN];
  __shared__ int hist[256];
  __shared__ int s_d, s_need, s_gt, s_eq;
  const int row = blockIdx.x, t = threadIdx.x;
  for (int i = t; i < NN; i += 256) rowv[i] = GT[(size_t)row * NN + i];
  __syncthreads();
  unsigned prefix = 0;
  int need = KMID;
  for (int pass = 0; pass < 4; ++pass) {
    hist[t] = 0;
    __syncthreads();
    const int shift = 24 - 8 * pass;
    for (int i = t; i < NN; i += 256) {
      unsigned k = f2key(rowv[i]);
      if (pass == 0 || (k >> (shift + 8)) == (prefix >> (shift + 8)))
        atomicAdd(&hist[(k >> shift) & 0xFF], 1);
    }
    __syncthreads();
    if (t == 0) {
      int cum = 0, d = 255;
      for (; d > 0; --d) {
        if (cum + hist[d] >= need) break;
        cum += hist[d];
      }
      s_d = d;
      s_need = need - cum;
    }
    __syncthreads();
    prefix |= ((unsigned)s_d) << shift;
    need = s_need;
    __syncthreads();
  }
  const unsigned thrk = prefix;
  if (t == 0) { s_gt = 0; s_eq = 0; thr[row] = key2f(thrk); }
  __syncthreads();
  for (int i = t; i < NN; i += 256) {
    if (f2key(rowv[i]) > thrk) {
      int p = atomicAdd(&s_gt, 1);
      cand[(size_t)row * KMID + p] = make_uint2(__float_as_uint(rowv[i]), (unsigned)i);
    }
  }
  __syncthreads();
  const int cgt = s_gt;
  for (int i = t; i < NN; i += 256) {
    if (f2key(rowv[i]) == thrk) {
      int p = atomicAdd(&s_eq, 1);
      if (p < KMID - cgt)
        cand[(size_t)row * KMID + cgt + p] = make_uint2(__float_as_uint(rowv[i]), (unsigned)i);
    }
  }
}

// DPP merge of (bv,bi): max value, smallest index on ties.
#define DPP_MERGE2(CTRL)                                                      \
  {                                                                           \
    int ovb = __builtin_amdgcn_update_dpp(                                    \
        (int)0xFF800000, __float_as_int(bv), (CTRL), 0xf, 0xf, false);        \
    int oib = __builtin_amdgcn_update_dpp(                                    \
        0x7fffffff, bi, (CTRL), 0xf, 0xf, false);                             \
    float ov = __int_as_float(ovb);                                           \
    if (ov > bv || (ov == bv && oib < bi)) { bv = ov; bi = oib; }             \
  }

// ---------------- per-row top-5 of the KMID list (one wave per row) ---------------
__global__ __launch_bounds__(64) void prep_top5(const uint2* __restrict__ cand,
                                                unsigned* __restrict__ c5,
                                                unsigned* __restrict__ gmaxA) {
  const int row = blockIdx.x, lane = threadIdx.x;
  uint2 e0 = cand[(size_t)row * KMID + lane];
  uint2 e1 = cand[(size_t)row * KMID + 64 + lane];
  float g0 = __uint_as_float(e0.x), g1 = __uint_as_float(e1.x);
  float am = 0.f;
  for (int k = 0; k < 5; ++k) {
    float bv; int bi;
    if (g0 >= g1) { bv = g0; bi = lane * 2; } else { bv = g1; bi = lane * 2 + 1; }
    DPP_MERGE2(0x111); DPP_MERGE2(0x112); DPP_MERGE2(0x114);
    DPP_MERGE2(0x118); DPP_MERGE2(0x142); DPP_MERGE2(0x143);
    float wv = __int_as_float(__builtin_amdgcn_readlane(__float_as_int(bv), 63));
    int wenc = __builtin_amdgcn_readlane(bi, 63);
    if (lane == (wenc >> 1)) {
      unsigned idx = (wenc & 1) ? e1.y : e0.y;
      c5[row * TSTR + k] = ((unsigned)f2bf_rn(wv) << 16) | (idx & 0xffffu);
      if (k == 4) c5[row * TSTR + 5] = __float_as_uint(wv);  // thr5 fp32
      if (wenc & 1) g1 = -__builtin_inff(); else g0 = -__builtin_inff();
    }
    am = fmaxf(am, fabsf(wv));
  }
  if (lane == 0) atomicMax(gmaxA, __float_as_uint(am));  // am >= 0: monotonic
}

// ---------------- L2 pre-warm ----------------
__global__ __launch_bounds__(256) void warm_k(const float* __restrict__ a, int n,
                                              const float* __restrict__ b, int m,
                                              float* __restrict__ sink) {
  float s = 0.f;
  const float4* a4 = (const float4*)a;
  for (int i = threadIdx.x; i < n / 4; i += 256) {
    float4 x = a4[i];
    s += x.x + x.y + x.z + x.w;
  }
  for (int i = threadIdx.x; i < m; i += 256) s += b[i];
  if (s == 1.2345e-30f) sink[blockIdx.x] = s;
}

// Top-2 DPP merge for tier 1: carries (v1, i1, v2).
#define TOP2_MERGE(CTRL)                                                      \
  {                                                                           \
    int ov1b = __builtin_amdgcn_update_dpp(                                   \
        (int)0xFF800000, __float_as_int(v1), (CTRL), 0xf, 0xf, false);        \
    int oi1b = __builtin_amdgcn_update_dpp(                                   \
        0x7fffffff, i1, (CTRL), 0xf, 0xf, false);                             \
    int ov2b = __builtin_amdgcn_update_dpp(                                   \
        (int)0xFF800000, __float_as_int(v2), (CTRL), 0xf, 0xf, false);        \
    float ov1 = __int_as_float(ov1b), ov2 = __int_as_float(ov2b);             \
    float vmax = fmaxf(v1, ov1), vmin = fminf(v1, ov1);                       \
    v2 = fmaxf(vmin, fmaxf(v2, ov2));                                         \
    i1 = (ov1 > v1) ? oi1b : ((ov1 < v1) ? i1 : min(i1, oi1b));               \
    v1 = vmax;                                                                \
  }

// ---------------- sequential decode: ONE wave, 3 tiers, NO unconditional loads ----
__global__ __launch_bounds__(64, 1) void decode(const float* __restrict__ GT,
                                                const uint2* __restrict__ cand,
                                                const float* __restrict__ thrp,
                                                const unsigned* __restrict__ c5g,
                                                const unsigned* __restrict__ ub16,
                                                const unsigned* __restrict__ gmaxA,
                                                const float* __restrict__ umaxp,
                                                const float* __restrict__ u,
                                                const float* __restrict__ demands,
                                                const int* __restrict__ capp,
                                                const int* __restrict__ depotp,
                                                int* __restrict__ tourW,
                                                float* __restrict__ lrW,
                                                float* __restrict__ out) {
  __shared__ __align__(16) unsigned s_c5[NN * TSTR];      // 48 KB top-5 table
  __shared__ __align__(16) float s_dd[NN];                // 8 KB demands/+inf
  __shared__ __align__(16) unsigned short s_ub[NN];       // 4 KB bf16 u

  const int lane = threadIdx.x;
  const int depot = *depotp;
  const float capf = (float)(*capp);
  const float umaxv = *umaxp;
  const float gmaxv = __uint_as_float(*gmaxA);
  const float INF = __builtin_inff();
  const float NEGINF = -INF;
  const float C0 = 0.015625f;   // ALPHA / sqrt(HID), exact power of two
  const float EPST = (gmaxv + umaxv) * 0.0021f + 0.02f;  // >= bf16+fma error

  for (int i = lane; i < NN * TSTR / 4; i += 64)
    ((uint4*)s_c5)[i] = ((const uint4*)c5g)[i];
  for (int i = lane; i < NN; i += 64) s_dd[i] = demands[i];
  for (int i = lane; i < NN / 2; i += 64) ((unsigned*)s_ub)[i] = ub16[i];
  __syncthreads();
  if (lane == 0) s_dd[depot] = INF;  // depot starts visited

  float uu[32];  // R9 layout for tier-3: uu[r*4+j] = u[4*(r*64+lane)+j]
#pragma unroll
  for (int r = 0; r < 8; ++r) {
    float4 u4 = ((const float4*)u)[r * 64 + lane];
    uu[r * 4 + 0] = u4.x; uu[r * 4 + 1] = u4.y;
    uu[r * 4 + 2] = u4.z; uu[r * 4 + 3] = u4.w;
  }
  const float4* dd4 = (const float4*)s_dd;

  int done = 0, ntaken = 0, lasts = depot;
  float load = capf;
  float lr = load / capf;  // same fp32 division as reference

  for (int step = 0; step < TSTEPS; ++step) {
    if (done) {  // ref emits (depot, 0) forever once done
      for (int q = step + lane; q < TSTEPS; q += 64) {
        tourW[q] = depot;
        lrW[q] = -1.0f;
      }
      break;
    }
    // ================= TIER 1: pure-LDS top-5 (no global access) =================
    unsigned w = 0;
    if (lane < 6) w = s_c5[lasts * TSTR + lane];
    float v1 = NEGINF, v2 = NEGINF;
    int i1 = 0x7fffffff;
    if (lane < 5) {
      int idx = (int)(w & 0xffffu);
      float gh = __uint_as_float(w & 0xffff0000u);
      float uh = __uint_as_float(((unsigned)s_ub[idx]) << 16);
      float d = s_dd[idx];                     // +inf == visited
      float t = fmaf(uh, lr, gh);
      if (d <= load) { v1 = t; i1 = idx; }
    }
    TOP2_MERGE(0x111); TOP2_MERGE(0x112); TOP2_MERGE(0x114);  // lane 7 = lanes 0..7
    const float s1 = __int_as_float(__builtin_amdgcn_readlane(__float_as_int(v1), 7));
    const float s2 = __int_as_float(__builtin_amdgcn_readlane(__float_as_int(v2), 7));
    const int si = __builtin_amdgcn_readlane(i1, 7);
    const float thr5v = __uint_as_float(__builtin_amdgcn_readlane((int)w, 5));
    const float slack = fmaf(lr, umaxv, 0.5f) + EPST;

    int take, nxt;
    if (s1 - EPST > s2 + EPST && s1 - EPST > thr5v + slack) {
      take = 1; nxt = si;  // certified exact global argmax
    } else {
      // ============ TIER 2: on-demand exact K=128 (R9-verbatim) ============
      const uint4* rc4 = (const uint4*)(cand + (size_t)lasts * KMID);
      const uint4 c4 = rc4[lane];           // 2 uint2 entries
      const float thrm = thrp[lasts];       // broadcast load (L1/L2-hot)
      float bv = NEGINF;
      int bi = 0x7fffffff;
      {
        float g0 = __uint_as_float(c4.x); int j0 = (int)c4.y;
        float g1 = __uint_as_float(c4.z); int j1 = (int)c4.w;
        float d0 = s_dd[j0], d1 = s_dd[j1];
        float ue0 = u[j0], ue1 = u[j1];     // exact u (8 KB, L1-hot)
        float t0 = fmaf(ue0, lr, g0);
        float t1 = fmaf(ue1, lr, g1);
        if ((d0 <= load) && (t0 > bv || (t0 == bv && j0 < bi))) { bv = t0; bi = j0; }
        if ((d1 <= load) && (t1 > bv || (t1 == bv && j1 < bi))) { bv = t1; bi = j1; }
      }
      DPP_MERGE2(0x111); DPP_MERGE2(0x112); DPP_MERGE2(0x114);
      DPP_MERGE2(0x118); DPP_MERGE2(0x142); DPP_MERGE2(0x143);
      float rbv = __int_as_float(__builtin_amdgcn_readlane(__float_as_int(bv), 63));
      int rbi = __builtin_amdgcn_readlane(bi, 63);
      if (rbv > fmaf(lr, umaxv, thrm) + 0.5f) {  // exact certification (R8/R9)
        take = 1; nxt = rbi;
      } else {
        // ============ TIER 3: full-row scan (R9-verbatim) ============
        const float4* rowp = (const float4*)(GT + (size_t)lasts * NN);
        float bv = NEGINF;
        int bi = NN;
#pragma unroll
        for (int r = 0; r < 8; ++r) {
          float4 g4 = rowp[r * 64 + lane];
          float4 d4 = dd4[r * 64 + lane];
          float gl[4] = {g4.x, g4.y, g4.z, g4.w};
          float dl[4] = {d4.x, d4.y, d4.z, d4.w};
          float cv = NEGINF;
          int cj = 0;
#pragma unroll
          for (int j = 0; j < 4; ++j) {
            float tt = fmaf(uu[r * 4 + j], lr, gl[j]);
            bool feas = (dl[j] <= load);
            if (feas && tt > cv) { cv = tt; cj = j; }
          }
          if (cv > bv) { bv = cv; bi = 4 * (r * 64 + lane) + cj; }
        }
        DPP_MERGE2(0x111); DPP_MERGE2(0x112); DPP_MERGE2(0x114);
        DPP_MERGE2(0x118); DPP_MERGE2(0x142); DPP_MERGE2(0x143);
        float fbv = __int_as_float(__builtin_amdgcn_readlane(__float_as_int(bv), 63));
        int fbi = __builtin_amdgcn_readlane(bi, 63);
        take = (fbv > NEGINF);
        nxt = take ? fbi : depot;
      }
    }

    // ---- state update + off-chain output stores
    if (lane == 0) { tourW[step] = nxt; lrW[step] = take ? lr : -1.0f; }
    if (take) {
      float dsel = s_dd[nxt];   // original demand (winner unvisited)
      load = load - dsel;       // same fp32 op sequence as reference
      ntaken++;
      if (lane == 0) s_dd[nxt] = INF;
    } else {
      load = capf;
      if (ntaken == NN - 1) done = 1;
    }
    lasts = nxt;
    lr = load / capf;  // same fp32 division as reference
  }

  // ---- deferred exact outputs
  __threadfence();
  if (lane == 0) out[0] = (float)depot;
  for (int s = lane; s < TSTEPS; s += 64) {
    int nx = tourW[s];
    out[1 + s] = (float)nx;
    float lrs = lrW[s];
    float sc = 0.0f;
    if (lrs >= 0.0f) {
      int lastI = (s == 0) ? depot : tourW[s - 1];
      float g = GT[(size_t)lastI * NN + nx];
      sc = fmaf(u[nx], lrs, g) * C0;  // identical expression to R3-R11
    }
    out[1 + TSTEPS + s] = sc;
  }
}

extern "C" void kernel_launch(void* const* d_in, const int* in_sizes, int n_in,
                              void* d_out, int out_size, void* d_ws, size_t ws_size,
                              hipStream_t stream) {
  const float* emb     = (const float*)d_in[0];  // [N, H]
  const float* demands = (const float*)d_in[1];  // [N]
  const float* Wq      = (const float*)d_in[2];  // [H, H+2]
  const float* bq      = (const float*)d_in[3];  // [H]
  const float* Wk      = (const float*)d_in[4];  // [H, H]
  const float* bk      = (const float*)d_in[5];  // [H]
  const int* cap       = (const int*)d_in[6];
  const int* depot     = (const int*)d_in[7];
  float* out           = (float*)d_out;          // 2305 tour + 2304 scores, fp32

  char* ws = (char*)d_ws;
  float* Kmat = (float*)(ws);                         // 8 MB  [N,H]
  float* Z    = (float*)(ws + ((size_t)8 << 20));     // 8 MB  [N,H]
  float* GT   = (float*)(ws + ((size_t)16 << 20));    // 16 MB [N,N] row=last, +v
  float* Wqh  = (float*)(ws + ((size_t)32 << 20));    // 4 MB; later cand (2 MB)
  char* ex    = ws + ((size_t)36 << 20);
  float* u      = (float*)(ex);                       // 8 KB
  float* v      = (float*)(ex + 8192);                // 8 KB
  float* thr    = (float*)(ex + 16384);               // 8 KB
  float* umax   = (float*)(ex + 24576);
  unsigned* gmaxA = (unsigned*)(ex + 24704);
  float* sink   = (float*)(ex + 24832);
  unsigned* ub16 = (unsigned*)(ex + 32768);           // 4 KB
  unsigned* c5g  = (unsigned*)(ex + 40960);           // 48 KB
  int* tourW    = (int*)(ex + 40960 + 49152);         // 9.2 KB
  float* lrW    = (float*)(ex + 40960 + 49152 + 9216);// 9.2 KB
  uint2* cnd    = (uint2*)Wqh;                        // 2 MB; Wqh dead after Z

  hipLaunchKernelGGL(prep_wqh, dim3(4096), dim3(256), 0, stream, Wq, Wqh);
  hipLaunchKernelGGL(gemm_nt, dim3(HH / TILE, NN / TILE), dim3(256), 0, stream,
                     emb, HH, Wk, HH, Kmat, HH, HH, bk);
  hipLaunchKernelGGL(gemm_nt, dim3(HH / TILE, NN / TILE), dim3(256), 0, stream,
                     emb, HH, Wqh, HH, Z, HH, HH, (const float*)nullptr);
  hipLaunchKernelGGL(uv_k, dim3(NN), dim3(64), 0, stream, Kmat, Wq, bq, u, v);
  hipLaunchKernelGGL(umax_k, dim3(1), dim3(256), 0, stream, u, umax, gmaxA, ub16);
  hipLaunchKernelGGL(gemm_nt, dim3(NN / TILE, NN / TILE), dim3(256), 0, stream,
                     Z, HH, Kmat, HH, GT, NN, HH, v);
  hipLaunchKernelGGL(prep_cand, dim3(NN), dim3(256), 0, stream, GT, cnd, thr);
  hipLaunchKernelGGL(prep_top5, dim3(NN), dim3(64), 0, stream, cnd, c5g, gmaxA);
  hipLaunchKernelGGL(warm_k, dim3(128), dim3(256), 0, stream,
                     (const float*)cnd, NN * KMID * 2, thr, NN, sink);
  hipLaunchKernelGGL(decode, dim3(1), dim3(64), 0, stream, GT, cnd, thr, c5g,
                     ub16, gmaxA, umax, u, demands, cap, depot, tourW, lrW, out);
}